// Round 1
// baseline (876.400 us; speedup 1.0000x reference)
//
#include <hip/hip_runtime.h>

#define N_NODES 50000
#define N_EDGES 1600000
#define IN_F 256
#define NEG_SLOPE 0.2f

// ---------------- K1: ft = feat @ W  (50000x256 @ 256x128, f32) ----------------
// Block 256: 128 cols x 2 row-groups of 16 rows. W k-tile (64x128) in LDS,
// feat tile transposed in LDS with stride 33 (conflict-free), 16 acc regs/thread.
__global__ __launch_bounds__(256) void k_gemm(const float* __restrict__ feat,
                                              const float* __restrict__ W,
                                              float* __restrict__ ft) {
  __shared__ float Wl[64 * 128];   // 32 KB
  __shared__ float Fl[64 * 33];    // 8.4 KB, padded stride 33 -> conflict-free
  const int tid = threadIdx.x;
  const int c = tid & 127;
  const int rg = tid >> 7;
  const int row0 = blockIdx.x * 32;
  float acc[16];
#pragma unroll
  for (int r = 0; r < 16; ++r) acc[r] = 0.f;
  for (int kt = 0; kt < IN_F; kt += 64) {
    __syncthreads();
    for (int i = tid; i < 64 * 128; i += 256) Wl[i] = W[kt * 128 + i];
#pragma unroll
    for (int j = 0; j < 8; ++j) {
      int idx = tid + j * 256;
      int k = idx & 63, r = idx >> 6;
      int row = row0 + r;
      if (row >= N_NODES) row = N_NODES - 1;   // clamp (stores are guarded)
      Fl[k * 33 + r] = feat[row * IN_F + kt + k];
    }
    __syncthreads();
    for (int k = 0; k < 64; ++k) {
      float w = Wl[k * 128 + c];
      const float* fp = &Fl[k * 33 + rg * 16];
#pragma unroll
      for (int r = 0; r < 16; ++r) acc[r] = fmaf(fp[r], w, acc[r]);
    }
  }
#pragma unroll
  for (int r = 0; r < 16; ++r) {
    int row = row0 + rg * 16 + r;
    if (row < N_NODES) ft[row * 128 + c] = acc[r];
  }
}

// ---------------- K2: el/er per node (wave per node, lanes = 64 feats) ----------
__global__ __launch_bounds__(256) void k_elr(const float* __restrict__ ft,
                                             const float* __restrict__ attn_l,
                                             const float* __restrict__ attn_r,
                                             float* __restrict__ el,
                                             float* __restrict__ er) {
  int t = blockIdx.x * 256 + threadIdx.x;
  int gw = t >> 6, lane = t & 63;
  if (gw >= N_NODES) return;
  float f0 = ft[gw * 128 + lane];
  float f1 = ft[gw * 128 + 64 + lane];
  float v0 = f0 * attn_l[lane];
  float v1 = f1 * attn_l[64 + lane];
  float v2 = f0 * attn_r[lane];
  float v3 = f1 * attn_r[64 + lane];
#pragma unroll
  for (int m = 32; m > 0; m >>= 1) {
    v0 += __shfl_xor(v0, m, 64);
    v1 += __shfl_xor(v1, m, 64);
    v2 += __shfl_xor(v2, m, 64);
    v3 += __shfl_xor(v3, m, 64);
  }
  if (lane == 0) {
    el[gw * 2] = v0; el[gw * 2 + 1] = v1;
    er[gw * 2] = v2; er[gw * 2 + 1] = v3;
  }
}

// ---------------- K3: edge logits -> exp, sum per dst, degree histogram --------
// No segment-max needed: softmax ratio is invariant to the shift; |e| <~ 6.
__global__ __launch_bounds__(256) void k_edge(const int* __restrict__ src,
                                              const int* __restrict__ dst,
                                              const float* __restrict__ el,
                                              const float* __restrict__ er,
                                              float* __restrict__ pbuf,
                                              float* __restrict__ ssum,
                                              int* __restrict__ deg) {
  int e = blockIdx.x * 256 + threadIdx.x;
  if (e >= N_EDGES) return;
  int s = src[e], d = dst[e];
  float2 a = ((const float2*)el)[s];
  float2 b = ((const float2*)er)[d];
  float e0 = a.x + b.x, e1 = a.y + b.y;
  e0 = e0 > 0.f ? e0 : NEG_SLOPE * e0;
  e1 = e1 > 0.f ? e1 : NEG_SLOPE * e1;
  float p0 = expf(e0), p1 = expf(e1);
  ((float2*)pbuf)[e] = make_float2(p0, p1);
  atomicAdd(&ssum[d * 2], p0);
  atomicAdd(&ssum[d * 2 + 1], p1);
  atomicAdd(&deg[d], 1);
}

// ---------------- K4: exclusive scan of degrees (single block, 16 waves) -------
__global__ void k_scan(const int* __restrict__ deg, int* __restrict__ rowptr,
                       int* __restrict__ cursor) {
  __shared__ int wsum[16];
  __shared__ int carry_s;
  int tid = threadIdx.x, lane = tid & 63, w = tid >> 6;
  if (tid == 0) carry_s = 0;
  __syncthreads();
  for (int base = 0; base < N_NODES; base += 1024) {
    int i = base + tid;
    int v = (i < N_NODES) ? deg[i] : 0;
    int x = v;
#pragma unroll
    for (int off = 1; off < 64; off <<= 1) {
      int y = __shfl_up(x, off, 64);
      if (lane >= off) x += y;
    }
    if (lane == 63) wsum[w] = x;
    __syncthreads();
    if (w == 0 && lane < 16) {
      int sv = wsum[lane];
#pragma unroll
      for (int off = 1; off < 16; off <<= 1) {
        int y = __shfl_up(sv, off, 64);
        if (lane >= off) sv += y;
      }
      wsum[lane] = sv;
    }
    __syncthreads();
    int carry = carry_s;
    int woff = (w == 0) ? 0 : wsum[w - 1];
    int excl = carry + woff + x - v;
    if (i < N_NODES) { rowptr[i] = excl; cursor[i] = excl; }
    __syncthreads();
    if (tid == 0) carry_s = carry + wsum[15];
    __syncthreads();
  }
  if (threadIdx.x == 0) rowptr[N_NODES] = carry_s;
}

// ---------------- K5: scatter edges into CSR records {src, a0, a1, pad} --------
__global__ __launch_bounds__(256) void k_scatter(const int* __restrict__ src,
                                                 const int* __restrict__ dst,
                                                 const float* __restrict__ pbuf,
                                                 const float* __restrict__ ssum,
                                                 int* __restrict__ cursor,
                                                 float4* __restrict__ rec) {
  int e = blockIdx.x * 256 + threadIdx.x;
  if (e >= N_EDGES) return;
  int s = src[e], d = dst[e];
  float2 p = ((const float2*)pbuf)[e];
  float2 sv = ((const float2*)ssum)[d];
  float a0 = p.x / fmaxf(sv.x, 1e-20f);
  float a1 = p.y / fmaxf(sv.y, 1e-20f);
  int pos = atomicAdd(&cursor[d], 1);
  rec[pos] = make_float4(__int_as_float(s), a0, a1, 0.f);
}

// ---------------- K6: aggregation, wave per (node, head), lanes = 64 feats -----
// Atomic-free: each wave owns its output row segment.
__global__ __launch_bounds__(256) void k_agg(const float4* __restrict__ rec,
                                             const int* __restrict__ rowptr,
                                             const float* __restrict__ ft,
                                             float* __restrict__ out) {
  int t = blockIdx.x * 256 + threadIdx.x;
  int gw = t >> 6, lane = t & 63;
  if (gw >= N_NODES * 2) return;
  int node = gw >> 1, h = gw & 1;
  int beg = rowptr[node], end = rowptr[node + 1];
  float acc = 0.f;
  for (int i = beg; i < end; ++i) {
    float4 r = rec[i];
    int s = __float_as_int(r.x);
    float a = h ? r.z : r.y;
    acc = fmaf(a, ft[s * 128 + h * 64 + lane], acc);
  }
  out[node * 128 + h * 64 + lane] = acc;
}

extern "C" void kernel_launch(void* const* d_in, const int* in_sizes, int n_in,
                              void* d_out, int out_size, void* d_ws, size_t ws_size,
                              hipStream_t stream) {
  const float* feat   = (const float*)d_in[0];
  const int*   src    = (const int*)d_in[1];
  const int*   dst    = (const int*)d_in[2];
  const float* W      = (const float*)d_in[3];
  const float* attn_l = (const float*)d_in[4];
  const float* attn_r = (const float*)d_in[5];
  float* out = (float*)d_out;

  char* base = (char*)d_ws;
  size_t off = 0;
  auto bump = [&](size_t bytes) -> void* {
    void* p = base + off;
    off = (off + bytes + 255) & ~(size_t)255;
    return p;
  };
  float*  ft     = (float*)bump(sizeof(float) * N_NODES * 128);   // 25.6 MB
  float*  el     = (float*)bump(sizeof(float) * N_NODES * 2);
  float*  er     = (float*)bump(sizeof(float) * N_NODES * 2);
  float*  ssum   = (float*)bump(sizeof(float) * N_NODES * 2);
  float*  pbuf   = (float*)bump(sizeof(float) * N_EDGES * 2);     // 12.8 MB
  int*    deg    = (int*)bump(sizeof(int) * N_NODES);
  int*    rowptr = (int*)bump(sizeof(int) * (N_NODES + 1));
  int*    cursor = (int*)bump(sizeof(int) * N_NODES);
  float4* rec    = (float4*)bump(sizeof(float4) * N_EDGES);       // 25.6 MB
  (void)ws_size; (void)in_sizes; (void)n_in; (void)out_size;

  hipMemsetAsync(ssum, 0, sizeof(float) * N_NODES * 2, stream);
  hipMemsetAsync(deg, 0, sizeof(int) * N_NODES, stream);

  k_gemm<<<(N_NODES + 31) / 32, 256, 0, stream>>>(feat, W, ft);
  k_elr<<<(N_NODES * 64 + 255) / 256, 256, 0, stream>>>(ft, attn_l, attn_r, el, er);
  k_edge<<<(N_EDGES + 255) / 256, 256, 0, stream>>>(src, dst, el, er, pbuf, ssum, deg);
  k_scan<<<1, 1024, 0, stream>>>(deg, rowptr, cursor);
  k_scatter<<<(N_EDGES + 255) / 256, 256, 0, stream>>>(src, dst, pbuf, ssum, cursor, rec);
  k_agg<<<(N_NODES * 2 * 64 + 255) / 256, 256, 0, stream>>>(rec, rowptr, ft, out);
}

// Round 2
// 495.554 us; speedup vs baseline: 1.7685x; 1.7685x over previous
//
#include <hip/hip_runtime.h>

#define N_NODES 50000
#define N_EDGES 1600000
#define IN_F 256
#define NEG_SLOPE 0.2f
#define CHUNK 1024
#define NCH ((N_NODES + CHUNK - 1) / CHUNK)   // 49

// ---------------- K1: ft = feat @ W  (50000x256 @ 256x128, f32) ----------------
__global__ __launch_bounds__(256) void k_gemm(const float* __restrict__ feat,
                                              const float* __restrict__ W,
                                              float* __restrict__ ft) {
  __shared__ float Wl[64 * 128];   // 32 KB
  __shared__ float Fl[64 * 33];    // padded stride 33 -> conflict-free
  const int tid = threadIdx.x;
  const int c = tid & 127;
  const int rg = tid >> 7;
  const int row0 = blockIdx.x * 32;
  float acc[16];
#pragma unroll
  for (int r = 0; r < 16; ++r) acc[r] = 0.f;
  for (int kt = 0; kt < IN_F; kt += 64) {
    __syncthreads();
    for (int i = tid; i < 64 * 128; i += 256) Wl[i] = W[kt * 128 + i];
#pragma unroll
    for (int j = 0; j < 8; ++j) {
      int idx = tid + j * 256;
      int k = idx & 63, r = idx >> 6;
      int row = row0 + r;
      if (row >= N_NODES) row = N_NODES - 1;   // clamp (stores are guarded)
      Fl[k * 33 + r] = feat[row * IN_F + kt + k];
    }
    __syncthreads();
    for (int k = 0; k < 64; ++k) {
      float w = Wl[k * 128 + c];
      const float* fp = &Fl[k * 33 + rg * 16];
#pragma unroll
      for (int r = 0; r < 16; ++r) acc[r] = fmaf(fp[r], w, acc[r]);
    }
  }
#pragma unroll
  for (int r = 0; r < 16; ++r) {
    int row = row0 + rg * 16 + r;
    if (row < N_NODES) ft[row * 128 + c] = acc[r];
  }
}

// ---------------- K2: el/er per node (wave per node, lanes = 64 feats) ----------
__global__ __launch_bounds__(256) void k_elr(const float* __restrict__ ft,
                                             const float* __restrict__ attn_l,
                                             const float* __restrict__ attn_r,
                                             float* __restrict__ el,
                                             float* __restrict__ er) {
  int t = blockIdx.x * 256 + threadIdx.x;
  int gw = t >> 6, lane = t & 63;
  if (gw >= N_NODES) return;
  float f0 = ft[gw * 128 + lane];
  float f1 = ft[gw * 128 + 64 + lane];
  float v0 = f0 * attn_l[lane];
  float v1 = f1 * attn_l[64 + lane];
  float v2 = f0 * attn_r[lane];
  float v3 = f1 * attn_r[64 + lane];
#pragma unroll
  for (int m = 32; m > 0; m >>= 1) {
    v0 += __shfl_xor(v0, m, 64);
    v1 += __shfl_xor(v1, m, 64);
    v2 += __shfl_xor(v2, m, 64);
    v3 += __shfl_xor(v3, m, 64);
  }
  if (lane == 0) {
    el[gw * 2] = v0; el[gw * 2 + 1] = v1;
    er[gw * 2] = v2; er[gw * 2 + 1] = v3;
  }
}

// ---------------- K3: degree histogram (int4-vectorized, 1 atomic/edge) --------
__global__ __launch_bounds__(256) void k_deg(const int* __restrict__ dst,
                                             int* __restrict__ deg) {
  int t = blockIdx.x * 256 + threadIdx.x;
  if (t >= N_EDGES / 4) return;
  int4 d4 = ((const int4*)dst)[t];
  atomicAdd(&deg[d4.x], 1);
  atomicAdd(&deg[d4.y], 1);
  atomicAdd(&deg[d4.z], 1);
  atomicAdd(&deg[d4.w], 1);
}

// ---------------- K4a: per-chunk sums -----------------------------------------
__global__ __launch_bounds__(256) void k_scanA(const int* __restrict__ deg,
                                               int* __restrict__ csum) {
  __shared__ int ws[4];
  int b = blockIdx.x, tid = threadIdx.x, lane = tid & 63, w = tid >> 6;
  int i0 = b * CHUNK + tid * 4;
  int s = 0;
#pragma unroll
  for (int j = 0; j < 4; ++j) {
    int i = i0 + j;
    if (i < N_NODES) s += deg[i];
  }
#pragma unroll
  for (int m = 32; m > 0; m >>= 1) s += __shfl_xor(s, m, 64);
  if (lane == 0) ws[w] = s;
  __syncthreads();
  if (tid == 0) csum[b] = ws[0] + ws[1] + ws[2] + ws[3];
}

// ---------------- K4b: 1-wave exclusive scan of chunk sums --------------------
__global__ void k_scanB(const int* __restrict__ csum, int* __restrict__ coff,
                        int* __restrict__ rowptr) {
  int tid = threadIdx.x;                  // 64 threads
  int v = (tid < NCH) ? csum[tid] : 0;
  int x = v;
#pragma unroll
  for (int off = 1; off < 64; off <<= 1) {
    int y = __shfl_up(x, off, 64);
    if (tid >= off) x += y;
  }
  if (tid < NCH) coff[tid] = x - v;       // exclusive
  if (tid == NCH - 1) rowptr[N_NODES] = x;
}

// ---------------- K4c: per-chunk exclusive rescan -> rowptr + cursor ----------
__global__ __launch_bounds__(256) void k_scanC(const int* __restrict__ deg,
                                               const int* __restrict__ coff,
                                               int* __restrict__ rowptr,
                                               int* __restrict__ cursor) {
  __shared__ int wtot[4];
  int b = blockIdx.x, tid = threadIdx.x, lane = tid & 63, w = tid >> 6;
  int i0 = b * CHUNK + tid * 4;
  int d[4];
#pragma unroll
  for (int j = 0; j < 4; ++j) d[j] = (i0 + j < N_NODES) ? deg[i0 + j] : 0;
  int t1 = d[0] + d[1], t2 = t1 + d[2], t3 = t2 + d[3];
  int x = t3;
#pragma unroll
  for (int off = 1; off < 64; off <<= 1) {
    int y = __shfl_up(x, off, 64);
    if (lane >= off) x += y;
  }
  if (lane == 63) wtot[w] = x;
  __syncthreads();
  int woff = 0;
  for (int j = 0; j < w; ++j) woff += wtot[j];
  int excl = coff[b] + woff + (x - t3);
  int pre[4] = {0, d[0], t1, t2};
#pragma unroll
  for (int j = 0; j < 4; ++j) {
    int i = i0 + j;
    if (i < N_NODES) { rowptr[i] = excl + pre[j]; cursor[i] = excl + pre[j]; }
  }
}

// ---------------- K5: scatter CSR records {src, p0, p1} (unnormalized) --------
__global__ __launch_bounds__(256) void k_scatter(const int* __restrict__ src,
                                                 const int* __restrict__ dst,
                                                 const float* __restrict__ el,
                                                 const float* __restrict__ er,
                                                 int* __restrict__ cursor,
                                                 float4* __restrict__ rec) {
  int e = blockIdx.x * 256 + threadIdx.x;
  if (e >= N_EDGES) return;
  int s = src[e], d = dst[e];
  float2 a = ((const float2*)el)[s];
  float2 b = ((const float2*)er)[d];
  float e0 = a.x + b.x, e1 = a.y + b.y;
  e0 = e0 > 0.f ? e0 : NEG_SLOPE * e0;
  e1 = e1 > 0.f ? e1 : NEG_SLOPE * e1;
  float p0 = __expf(e0), p1 = __expf(e1);
  int pos = atomicAdd(&cursor[d], 1);
  rec[pos] = make_float4(__int_as_float(s), p0, p1, 0.f);
}

// ---------------- K6: aggregation, wave per node, float2/lane, unroll x4 ------
// Softmax normalization fused here (divide by s at the end). Atomic-free.
__global__ __launch_bounds__(256) void k_agg(const float4* __restrict__ rec,
                                             const int* __restrict__ rowptr,
                                             const float* __restrict__ ft,
                                             float* __restrict__ out) {
  int t = blockIdx.x * 256 + threadIdx.x;
  int node = t >> 6, lane = t & 63;
  if (node >= N_NODES) return;
  int beg = rowptr[node], end = rowptr[node + 1];
  const float2* ft2 = (const float2*)ft;
  bool h1 = lane >= 32;                 // lanes 0-31: head0, 32-63: head1
  float ax = 0.f, ay = 0.f, s = 0.f;
  int i = beg;
  for (; i + 4 <= end; i += 4) {
    float4 r0 = rec[i], r1 = rec[i + 1], r2 = rec[i + 2], r3 = rec[i + 3];
    int s0 = __float_as_int(r0.x), s1 = __float_as_int(r1.x);
    int s2 = __float_as_int(r2.x), s3 = __float_as_int(r3.x);
    float2 f0 = ft2[s0 * 64 + lane];
    float2 f1 = ft2[s1 * 64 + lane];
    float2 f2 = ft2[s2 * 64 + lane];
    float2 f3 = ft2[s3 * 64 + lane];
    float a0 = h1 ? r0.z : r0.y;
    float a1 = h1 ? r1.z : r1.y;
    float a2 = h1 ? r2.z : r2.y;
    float a3 = h1 ? r3.z : r3.y;
    ax = fmaf(a0, f0.x, ax); ay = fmaf(a0, f0.y, ay);
    ax = fmaf(a1, f1.x, ax); ay = fmaf(a1, f1.y, ay);
    ax = fmaf(a2, f2.x, ax); ay = fmaf(a2, f2.y, ay);
    ax = fmaf(a3, f3.x, ax); ay = fmaf(a3, f3.y, ay);
    s += (a0 + a1) + (a2 + a3);
  }
  for (; i < end; ++i) {
    float4 r = rec[i];
    int sr = __float_as_int(r.x);
    float2 f = ft2[sr * 64 + lane];
    float a = h1 ? r.z : r.y;
    ax = fmaf(a, f.x, ax); ay = fmaf(a, f.y, ay);
    s += a;
  }
  float inv = 1.f / fmaxf(s, 1e-20f);
  ((float2*)out)[node * 64 + lane] = make_float2(ax * inv, ay * inv);
}

extern "C" void kernel_launch(void* const* d_in, const int* in_sizes, int n_in,
                              void* d_out, int out_size, void* d_ws, size_t ws_size,
                              hipStream_t stream) {
  const float* feat   = (const float*)d_in[0];
  const int*   src    = (const int*)d_in[1];
  const int*   dst    = (const int*)d_in[2];
  const float* W      = (const float*)d_in[3];
  const float* attn_l = (const float*)d_in[4];
  const float* attn_r = (const float*)d_in[5];
  float* out = (float*)d_out;

  char* base = (char*)d_ws;
  size_t off = 0;
  auto bump = [&](size_t bytes) -> void* {
    void* p = base + off;
    off = (off + bytes + 255) & ~(size_t)255;
    return p;
  };
  float*  ft     = (float*)bump(sizeof(float) * N_NODES * 128);   // 25.6 MB
  float*  el     = (float*)bump(sizeof(float) * N_NODES * 2);
  float*  er     = (float*)bump(sizeof(float) * N_NODES * 2);
  int*    deg    = (int*)bump(sizeof(int) * N_NODES);
  int*    csum   = (int*)bump(sizeof(int) * NCH);
  int*    coff   = (int*)bump(sizeof(int) * NCH);
  int*    rowptr = (int*)bump(sizeof(int) * (N_NODES + 1));
  int*    cursor = (int*)bump(sizeof(int) * N_NODES);
  float4* rec    = (float4*)bump(sizeof(float4) * N_EDGES);       // 25.6 MB
  (void)ws_size; (void)in_sizes; (void)n_in; (void)out_size;

  hipMemsetAsync(deg, 0, sizeof(int) * N_NODES, stream);

  k_gemm<<<(N_NODES + 31) / 32, 256, 0, stream>>>(feat, W, ft);
  k_elr<<<(N_NODES * 64 + 255) / 256, 256, 0, stream>>>(ft, attn_l, attn_r, el, er);
  k_deg<<<(N_EDGES / 4 + 255) / 256, 256, 0, stream>>>(dst, deg);
  k_scanA<<<NCH, 256, 0, stream>>>(deg, csum);
  k_scanB<<<1, 64, 0, stream>>>(csum, coff, rowptr);
  k_scanC<<<NCH, 256, 0, stream>>>(deg, coff, rowptr, cursor);
  k_scatter<<<(N_EDGES + 255) / 256, 256, 0, stream>>>(src, dst, el, er, cursor, rec);
  k_agg<<<(N_NODES * 64 + 255) / 256, 256, 0, stream>>>(rec, rowptr, ft, out);
}

// Round 3
// 413.680 us; speedup vs baseline: 2.1185x; 1.1979x over previous
//
#include <hip/hip_runtime.h>
#include <hip/hip_fp16.h>

#define N_NODES 50000
#define N_EDGES 1600000
#define IN_F 256
#define NEG_SLOPE 0.2f
#define CHUNK 1024
#define NCH ((N_NODES + CHUNK - 1) / CHUNK)   // 49

// ---- K1: ft = feat @ W (50000x256 @ 256x128) + fused el/er ------------------
// 64x128 tile, 256 thr, 4 rows x 8 cols per thread.
// Per k: 2x ds_read_b128 (W) + 4x ds_read_b32 (Fl, conflict-free) vs 32 FMA.
__global__ __launch_bounds__(256) void k_gemm(const float* __restrict__ feat,
                                              const float* __restrict__ W,
                                              const float* __restrict__ attn_l,
                                              const float* __restrict__ attn_r,
                                              float* __restrict__ ft,
                                              float* __restrict__ el,
                                              float* __restrict__ er) {
  __shared__ __align__(16) float Wl[32 * 128];   // 16 KB
  __shared__ __align__(16) float Fl[64 * 33];    // 8.4 KB, bank = (r+k)%32
  const int tid = threadIdx.x;
  const int cg = tid & 15;          // col group: cols cg*8 .. cg*8+7
  const int rg = tid >> 4;          // row group: rows rg*4 .. rg*4+3
  const int col0 = cg * 8, rowt = rg * 4;
  const int row0 = blockIdx.x * 64;
  float acc[4][8];
#pragma unroll
  for (int i = 0; i < 4; ++i)
#pragma unroll
    for (int j = 0; j < 8; ++j) acc[i][j] = 0.f;

  for (int kt = 0; kt < IN_F; kt += 32) {
    __syncthreads();
#pragma unroll
    for (int j = 0; j < 4; ++j) {                 // W chunk: 4096 f = 1024 f4
      int idx = tid + j * 256;
      ((float4*)Wl)[idx] = ((const float4*)(W + kt * 128))[idx];
    }
#pragma unroll
    for (int j = 0; j < 2; ++j) {                 // feat chunk: 64x32
      int r = j * 32 + (tid >> 3);
      int kk = (tid & 7) * 4;
      int grow = row0 + r;
      if (grow >= N_NODES) grow = N_NODES - 1;    // clamp; stores guarded
      float4 v = *(const float4*)(feat + (size_t)grow * IN_F + kt + kk);
      float* fp = &Fl[r * 33 + kk];
      fp[0] = v.x; fp[1] = v.y; fp[2] = v.z; fp[3] = v.w;
    }
    __syncthreads();
#pragma unroll
    for (int k = 0; k < 32; ++k) {
      float4 w0 = *(const float4*)&Wl[k * 128 + col0];
      float4 w1 = *(const float4*)&Wl[k * 128 + col0 + 4];
#pragma unroll
      for (int i = 0; i < 4; ++i) {
        float f = Fl[(rowt + i) * 33 + k];
        acc[i][0] = fmaf(f, w0.x, acc[i][0]);
        acc[i][1] = fmaf(f, w0.y, acc[i][1]);
        acc[i][2] = fmaf(f, w0.z, acc[i][2]);
        acc[i][3] = fmaf(f, w0.w, acc[i][3]);
        acc[i][4] = fmaf(f, w1.x, acc[i][4]);
        acc[i][5] = fmaf(f, w1.y, acc[i][5]);
        acc[i][6] = fmaf(f, w1.z, acc[i][6]);
        acc[i][7] = fmaf(f, w1.w, acc[i][7]);
      }
    }
  }
  // epilogue: store ft + fused per-head el/er (cols cg*8.. lie in one head)
  float al[8], ar[8];
#pragma unroll
  for (int j = 0; j < 8; ++j) { al[j] = attn_l[col0 + j]; ar[j] = attn_r[col0 + j]; }
#pragma unroll
  for (int i = 0; i < 4; ++i) {
    int row = row0 + rowt + i;
    float sl = 0.f, sr = 0.f;
#pragma unroll
    for (int j = 0; j < 8; ++j) { sl = fmaf(acc[i][j], al[j], sl); sr = fmaf(acc[i][j], ar[j], sr); }
#pragma unroll
    for (int m = 1; m < 8; m <<= 1) { sl += __shfl_xor(sl, m, 64); sr += __shfl_xor(sr, m, 64); }
    if (row < N_NODES) {
      *(float4*)(ft + (size_t)row * 128 + col0) =
          make_float4(acc[i][0], acc[i][1], acc[i][2], acc[i][3]);
      *(float4*)(ft + (size_t)row * 128 + col0 + 4) =
          make_float4(acc[i][4], acc[i][5], acc[i][6], acc[i][7]);
      if ((cg & 7) == 0) {
        int h = cg >> 3;                       // cg==0 -> head0, cg==8 -> head1
        el[row * 2 + h] = sl;
        er[row * 2 + h] = sr;
      }
    }
  }
}

// ---- K3: degree histogram (int4, 1 atomic/edge) -----------------------------
__global__ __launch_bounds__(256) void k_deg(const int* __restrict__ dst,
                                             int* __restrict__ deg) {
  int t = blockIdx.x * 256 + threadIdx.x;
  if (t >= N_EDGES / 4) return;
  int4 d4 = ((const int4*)dst)[t];
  atomicAdd(&deg[d4.x], 1);
  atomicAdd(&deg[d4.y], 1);
  atomicAdd(&deg[d4.z], 1);
  atomicAdd(&deg[d4.w], 1);
}

// ---- K4a/b/c: chunked exclusive scan ----------------------------------------
__global__ __launch_bounds__(256) void k_scanA(const int* __restrict__ deg,
                                               int* __restrict__ csum) {
  __shared__ int ws[4];
  int b = blockIdx.x, tid = threadIdx.x, lane = tid & 63, w = tid >> 6;
  int i0 = b * CHUNK + tid * 4;
  int s = 0;
#pragma unroll
  for (int j = 0; j < 4; ++j) {
    int i = i0 + j;
    if (i < N_NODES) s += deg[i];
  }
#pragma unroll
  for (int m = 32; m > 0; m >>= 1) s += __shfl_xor(s, m, 64);
  if (lane == 0) ws[w] = s;
  __syncthreads();
  if (tid == 0) csum[b] = ws[0] + ws[1] + ws[2] + ws[3];
}

__global__ void k_scanB(const int* __restrict__ csum, int* __restrict__ coff,
                        int* __restrict__ rowptr) {
  int tid = threadIdx.x;                  // 64 threads
  int v = (tid < NCH) ? csum[tid] : 0;
  int x = v;
#pragma unroll
  for (int off = 1; off < 64; off <<= 1) {
    int y = __shfl_up(x, off, 64);
    if (tid >= off) x += y;
  }
  if (tid < NCH) coff[tid] = x - v;
  if (tid == NCH - 1) rowptr[N_NODES] = x;
}

__global__ __launch_bounds__(256) void k_scanC(const int* __restrict__ deg,
                                               const int* __restrict__ coff,
                                               int* __restrict__ rowptr,
                                               int* __restrict__ cursor) {
  __shared__ int wtot[4];
  int b = blockIdx.x, tid = threadIdx.x, lane = tid & 63, w = tid >> 6;
  int i0 = b * CHUNK + tid * 4;
  int d[4];
#pragma unroll
  for (int j = 0; j < 4; ++j) d[j] = (i0 + j < N_NODES) ? deg[i0 + j] : 0;
  int t1 = d[0] + d[1], t2 = t1 + d[2], t3 = t2 + d[3];
  int x = t3;
#pragma unroll
  for (int off = 1; off < 64; off <<= 1) {
    int y = __shfl_up(x, off, 64);
    if (lane >= off) x += y;
  }
  if (lane == 63) wtot[w] = x;
  __syncthreads();
  int woff = 0;
  for (int j = 0; j < w; ++j) woff += wtot[j];
  int excl = coff[b] + woff + (x - t3);
  int pre[4] = {0, d[0], t1, t2};
#pragma unroll
  for (int j = 0; j < 4; ++j) {
    int i = i0 + j;
    if (i < N_NODES) { rowptr[i] = excl + pre[j]; cursor[i] = excl + pre[j]; }
  }
}

// ---- K5: scatter 8B CSR records {src, half2(p0,p1)} (unnormalized) ----------
__global__ __launch_bounds__(256) void k_scatter(const int* __restrict__ src,
                                                 const int* __restrict__ dst,
                                                 const float* __restrict__ el,
                                                 const float* __restrict__ er,
                                                 int* __restrict__ cursor,
                                                 uint2* __restrict__ rec) {
  int e = blockIdx.x * 256 + threadIdx.x;
  if (e >= N_EDGES) return;
  int s = src[e], d = dst[e];
  float2 a = ((const float2*)el)[s];
  float2 b = ((const float2*)er)[d];
  float e0 = a.x + b.x, e1 = a.y + b.y;
  e0 = e0 > 0.f ? e0 : NEG_SLOPE * e0;
  e1 = e1 > 0.f ? e1 : NEG_SLOPE * e1;
  __half2 h = __floats2half2_rn(__expf(e0), __expf(e1));
  int pos = atomicAdd(&cursor[d], 1);
  rec[pos] = make_uint2((unsigned)s, *(unsigned*)&h);
}

// ---- K6: aggregation, wave per node, float2/lane, unroll x4, fused softmax --
__global__ __launch_bounds__(256) void k_agg(const uint2* __restrict__ rec,
                                             const int* __restrict__ rowptr,
                                             const float* __restrict__ ft,
                                             float* __restrict__ out) {
  int t = blockIdx.x * 256 + threadIdx.x;
  int node = t >> 6, lane = t & 63;
  if (node >= N_NODES) return;
  int beg = rowptr[node], end = rowptr[node + 1];
  const float2* ft2 = (const float2*)ft;
  bool h1 = lane >= 32;                 // lanes 0-31: head0 feats, 32-63: head1
  float ax = 0.f, ay = 0.f, s = 0.f;
  int i = beg;
  for (; i + 4 <= end; i += 4) {
    uint2 r0 = rec[i], r1 = rec[i + 1], r2 = rec[i + 2], r3 = rec[i + 3];
    float2 p0 = __half22float2(*(const __half2*)&r0.y);
    float2 p1 = __half22float2(*(const __half2*)&r1.y);
    float2 p2 = __half22float2(*(const __half2*)&r2.y);
    float2 p3 = __half22float2(*(const __half2*)&r3.y);
    float2 f0 = ft2[(size_t)r0.x * 64 + lane];
    float2 f1 = ft2[(size_t)r1.x * 64 + lane];
    float2 f2 = ft2[(size_t)r2.x * 64 + lane];
    float2 f3 = ft2[(size_t)r3.x * 64 + lane];
    float a0 = h1 ? p0.y : p0.x;
    float a1 = h1 ? p1.y : p1.x;
    float a2 = h1 ? p2.y : p2.x;
    float a3 = h1 ? p3.y : p3.x;
    ax = fmaf(a0, f0.x, ax); ay = fmaf(a0, f0.y, ay);
    ax = fmaf(a1, f1.x, ax); ay = fmaf(a1, f1.y, ay);
    ax = fmaf(a2, f2.x, ax); ay = fmaf(a2, f2.y, ay);
    ax = fmaf(a3, f3.x, ax); ay = fmaf(a3, f3.y, ay);
    s += (a0 + a1) + (a2 + a3);
  }
  for (; i < end; ++i) {
    uint2 r = rec[i];
    float2 p = __half22float2(*(const __half2*)&r.y);
    float2 f = ft2[(size_t)r.x * 64 + lane];
    float a = h1 ? p.y : p.x;
    ax = fmaf(a, f.x, ax); ay = fmaf(a, f.y, ay);
    s += a;
  }
  float inv = 1.f / fmaxf(s, 1e-20f);
  ((float2*)out)[(size_t)node * 64 + lane] = make_float2(ax * inv, ay * inv);
}

extern "C" void kernel_launch(void* const* d_in, const int* in_sizes, int n_in,
                              void* d_out, int out_size, void* d_ws, size_t ws_size,
                              hipStream_t stream) {
  const float* feat   = (const float*)d_in[0];
  const int*   src    = (const int*)d_in[1];
  const int*   dst    = (const int*)d_in[2];
  const float* W      = (const float*)d_in[3];
  const float* attn_l = (const float*)d_in[4];
  const float* attn_r = (const float*)d_in[5];
  float* out = (float*)d_out;

  char* base = (char*)d_ws;
  size_t off = 0;
  auto bump = [&](size_t bytes) -> void* {
    void* p = base + off;
    off = (off + bytes + 255) & ~(size_t)255;
    return p;
  };
  float* ft     = (float*)bump(sizeof(float) * N_NODES * 128);   // 25.6 MB
  float* el     = (float*)bump(sizeof(float) * N_NODES * 2);
  float* er     = (float*)bump(sizeof(float) * N_NODES * 2);
  int*   deg    = (int*)bump(sizeof(int) * N_NODES);
  int*   csum   = (int*)bump(sizeof(int) * NCH);
  int*   coff   = (int*)bump(sizeof(int) * NCH);
  int*   rowptr = (int*)bump(sizeof(int) * (N_NODES + 1));
  int*   cursor = (int*)bump(sizeof(int) * N_NODES);
  uint2* rec    = (uint2*)bump(sizeof(uint2) * N_EDGES);         // 12.8 MB
  (void)ws_size; (void)in_sizes; (void)n_in; (void)out_size;

  hipMemsetAsync(deg, 0, sizeof(int) * N_NODES, stream);

  k_deg<<<(N_EDGES / 4 + 255) / 256, 256, 0, stream>>>(dst, deg);
  k_gemm<<<(N_NODES + 63) / 64, 256, 0, stream>>>(feat, W, attn_l, attn_r, ft, el, er);
  k_scanA<<<NCH, 256, 0, stream>>>(deg, csum);
  k_scanB<<<1, 64, 0, stream>>>(csum, coff, rowptr);
  k_scanC<<<NCH, 256, 0, stream>>>(deg, coff, rowptr, cursor);
  k_scatter<<<(N_EDGES + 255) / 256, 256, 0, stream>>>(src, dst, el, er, cursor, rec);
  k_agg<<<(N_NODES * 64 + 255) / 256, 256, 0, stream>>>(rec, rowptr, ft, out);
}

// Round 5
// 336.400 us; speedup vs baseline: 2.6052x; 1.2297x over previous
//
#include <hip/hip_runtime.h>
#include <hip/hip_fp16.h>

#define N_NODES 50000
#define N_EDGES 1600000
#define IN_F 256
#define NEG_SLOPE 0.2f
#define CHUNK 1024
#define NCH ((N_NODES + CHUNK - 1) / CHUNK)   // 49

// ---- K1: ft16 = half(feat @ W) + fused el/er --------------------------------
// 64x128 tile, 256 thr, 4 rows x 8 cols per thread. f32 accumulate, fp16 store.
__global__ __launch_bounds__(256) void k_gemm(const float* __restrict__ feat,
                                              const float* __restrict__ W,
                                              const float* __restrict__ attn_l,
                                              const float* __restrict__ attn_r,
                                              __half* __restrict__ ft16,
                                              float* __restrict__ el,
                                              float* __restrict__ er) {
  __shared__ __align__(16) float Wl[32 * 128];   // 16 KB
  __shared__ __align__(16) float Fl[64 * 33];    // 8.4 KB, bank = (r+k)%32
  const int tid = threadIdx.x;
  const int cg = tid & 15;          // col group: cols cg*8 .. cg*8+7
  const int rg = tid >> 4;          // row group: rows rg*4 .. rg*4+3
  const int col0 = cg * 8, rowt = rg * 4;
  const int row0 = blockIdx.x * 64;
  float acc[4][8];
#pragma unroll
  for (int i = 0; i < 4; ++i)
#pragma unroll
    for (int j = 0; j < 8; ++j) acc[i][j] = 0.f;

  for (int kt = 0; kt < IN_F; kt += 32) {
    __syncthreads();
#pragma unroll
    for (int j = 0; j < 4; ++j) {                 // W chunk: 32x128
      int idx = tid + j * 256;
      ((float4*)Wl)[idx] = ((const float4*)(W + kt * 128))[idx];
    }
#pragma unroll
    for (int j = 0; j < 2; ++j) {                 // feat chunk: 64x32
      int r = j * 32 + (tid >> 3);
      int kk = (tid & 7) * 4;
      int grow = row0 + r;
      if (grow >= N_NODES) grow = N_NODES - 1;    // clamp; stores guarded
      float4 v = *(const float4*)(feat + (size_t)grow * IN_F + kt + kk);
      float* fp = &Fl[r * 33 + kk];
      fp[0] = v.x; fp[1] = v.y; fp[2] = v.z; fp[3] = v.w;
    }
    __syncthreads();
#pragma unroll
    for (int k = 0; k < 32; ++k) {
      float4 w0 = *(const float4*)&Wl[k * 128 + col0];
      float4 w1 = *(const float4*)&Wl[k * 128 + col0 + 4];
#pragma unroll
      for (int i = 0; i < 4; ++i) {
        float f = Fl[(rowt + i) * 33 + k];
        acc[i][0] = fmaf(f, w0.x, acc[i][0]);
        acc[i][1] = fmaf(f, w0.y, acc[i][1]);
        acc[i][2] = fmaf(f, w0.z, acc[i][2]);
        acc[i][3] = fmaf(f, w0.w, acc[i][3]);
        acc[i][4] = fmaf(f, w1.x, acc[i][4]);
        acc[i][5] = fmaf(f, w1.y, acc[i][5]);
        acc[i][6] = fmaf(f, w1.z, acc[i][6]);
        acc[i][7] = fmaf(f, w1.w, acc[i][7]);
      }
    }
  }
  // epilogue: fp16 store + fused per-head el/er
  float al[8], ar[8];
#pragma unroll
  for (int j = 0; j < 8; ++j) { al[j] = attn_l[col0 + j]; ar[j] = attn_r[col0 + j]; }
#pragma unroll
  for (int i = 0; i < 4; ++i) {
    int row = row0 + rowt + i;
    float sl = 0.f, sr = 0.f;
#pragma unroll
    for (int j = 0; j < 8; ++j) { sl = fmaf(acc[i][j], al[j], sl); sr = fmaf(acc[i][j], ar[j], sr); }
#pragma unroll
    for (int m = 1; m < 8; m <<= 1) { sl += __shfl_xor(sl, m, 64); sr += __shfl_xor(sr, m, 64); }
    if (row < N_NODES) {
      __half2 h0 = __floats2half2_rn(acc[i][0], acc[i][1]);
      __half2 h1 = __floats2half2_rn(acc[i][2], acc[i][3]);
      __half2 h2 = __floats2half2_rn(acc[i][4], acc[i][5]);
      __half2 h3 = __floats2half2_rn(acc[i][6], acc[i][7]);
      uint4 pk = make_uint4(*(unsigned*)&h0, *(unsigned*)&h1,
                            *(unsigned*)&h2, *(unsigned*)&h3);
      *(uint4*)(ft16 + (size_t)row * 128 + col0) = pk;
      if ((cg & 7) == 0) {
        int h = cg >> 3;                       // cg==0 -> head0, cg==8 -> head1
        el[row * 2 + h] = sl;
        er[row * 2 + h] = sr;
      }
    }
  }
}

// ---- K2: degree histogram + within-segment rank (atomic return) -------------
__global__ __launch_bounds__(256) void k_deg(const int* __restrict__ dst,
                                             int* __restrict__ deg,
                                             ushort* __restrict__ rank) {
  int t = blockIdx.x * 256 + threadIdx.x;
  if (t >= N_EDGES / 4) return;
  int4 d4 = ((const int4*)dst)[t];
  ushort4 r;
  r.x = (ushort)atomicAdd(&deg[d4.x], 1);
  r.y = (ushort)atomicAdd(&deg[d4.y], 1);
  r.z = (ushort)atomicAdd(&deg[d4.z], 1);
  r.w = (ushort)atomicAdd(&deg[d4.w], 1);
  ((ushort4*)rank)[t] = r;
}

// ---- K3a/b/c: chunked exclusive scan ----------------------------------------
__global__ __launch_bounds__(256) void k_scanA(const int* __restrict__ deg,
                                               int* __restrict__ csum) {
  __shared__ int ws[4];
  int b = blockIdx.x, tid = threadIdx.x, lane = tid & 63, w = tid >> 6;
  int i0 = b * CHUNK + tid * 4;
  int s = 0;
#pragma unroll
  for (int j = 0; j < 4; ++j) {
    int i = i0 + j;
    if (i < N_NODES) s += deg[i];
  }
#pragma unroll
  for (int m = 32; m > 0; m >>= 1) s += __shfl_xor(s, m, 64);
  if (lane == 0) ws[w] = s;
  __syncthreads();
  if (tid == 0) csum[b] = ws[0] + ws[1] + ws[2] + ws[3];
}

__global__ void k_scanB(const int* __restrict__ csum, int* __restrict__ coff,
                        int* __restrict__ rowptr) {
  int tid = threadIdx.x;                  // 64 threads
  int v = (tid < NCH) ? csum[tid] : 0;
  int x = v;
#pragma unroll
  for (int off = 1; off < 64; off <<= 1) {
    int y = __shfl_up(x, off, 64);
    if (tid >= off) x += y;
  }
  if (tid < NCH) coff[tid] = x - v;
  if (tid == NCH - 1) rowptr[N_NODES] = x;
}

__global__ __launch_bounds__(256) void k_scanC(const int* __restrict__ deg,
                                               const int* __restrict__ coff,
                                               int* __restrict__ rowptr) {
  __shared__ int wtot[4];
  int b = blockIdx.x, tid = threadIdx.x, lane = tid & 63, w = tid >> 6;
  int i0 = b * CHUNK + tid * 4;
  int d[4];
#pragma unroll
  for (int j = 0; j < 4; ++j) d[j] = (i0 + j < N_NODES) ? deg[i0 + j] : 0;
  int t1 = d[0] + d[1], t2 = t1 + d[2], t3 = t2 + d[3];
  int x = t3;
#pragma unroll
  for (int off = 1; off < 64; off <<= 1) {
    int y = __shfl_up(x, off, 64);
    if (lane >= off) x += y;
  }
  if (lane == 63) wtot[w] = x;
  __syncthreads();
  int woff = 0;
  for (int j = 0; j < w; ++j) woff += wtot[j];
  int excl = coff[b] + woff + (x - t3);
  int pre[4] = {0, d[0], t1, t2};
#pragma unroll
  for (int j = 0; j < 4; ++j) {
    int i = i0 + j;
    if (i < N_NODES) rowptr[i] = excl + pre[j];
  }
}

// ---- K4: counting-sort of src by dst (atomic-free: pos = rowptr + rank) -----
__global__ __launch_bounds__(256) void k_sort(const int* __restrict__ src,
                                              const int* __restrict__ dst,
                                              const ushort* __restrict__ rank,
                                              const int* __restrict__ rowptr,
                                              int* __restrict__ srcs) {
  int t = blockIdx.x * 256 + threadIdx.x;
  if (t >= N_EDGES / 4) return;
  int4 s4 = ((const int4*)src)[t];
  int4 d4 = ((const int4*)dst)[t];
  ushort4 r4 = ((const ushort4*)rank)[t];
  srcs[rowptr[d4.x] + r4.x] = s4.x;
  srcs[rowptr[d4.y] + r4.y] = s4.y;
  srcs[rowptr[d4.z] + r4.z] = s4.z;
  srcs[rowptr[d4.w] + r4.w] = s4.w;
}

// ---- K5: aggregation, wave per node; p computed in-flight; fused softmax ----
__global__ __launch_bounds__(256) void k_agg(const int* __restrict__ srcs,
                                             const int* __restrict__ rowptr,
                                             const __half2* __restrict__ ft2,
                                             const float2* __restrict__ el2,
                                             const float2* __restrict__ er2,
                                             float2* __restrict__ out) {
  int t = blockIdx.x * 256 + threadIdx.x;
  int node = t >> 6, lane = t & 63;
  if (node >= N_NODES) return;
  int beg = rowptr[node], end = rowptr[node + 1];
  bool h1 = lane >= 32;                 // lanes 0-31: head0 feats, 32-63: head1
  float2 ern = er2[node];
  float erh = h1 ? ern.y : ern.x;
  float ax = 0.f, ay = 0.f, s = 0.f;
  int i = beg;
  for (; i + 4 <= end; i += 4) {
    int s0 = srcs[i], s1 = srcs[i + 1], s2 = srcs[i + 2], s3 = srcs[i + 3];
    float2 e0 = el2[s0], e1 = el2[s1], e2 = el2[s2], e3 = el2[s3];
    __half2 f0 = ft2[(size_t)s0 * 64 + lane];
    __half2 f1 = ft2[(size_t)s1 * 64 + lane];
    __half2 f2 = ft2[(size_t)s2 * 64 + lane];
    __half2 f3 = ft2[(size_t)s3 * 64 + lane];
    float x0 = (h1 ? e0.y : e0.x) + erh;
    float x1 = (h1 ? e1.y : e1.x) + erh;
    float x2 = (h1 ? e2.y : e2.x) + erh;
    float x3 = (h1 ? e3.y : e3.x) + erh;
    x0 = x0 > 0.f ? x0 : NEG_SLOPE * x0;
    x1 = x1 > 0.f ? x1 : NEG_SLOPE * x1;
    x2 = x2 > 0.f ? x2 : NEG_SLOPE * x2;
    x3 = x3 > 0.f ? x3 : NEG_SLOPE * x3;
    float p0 = __expf(x0), p1 = __expf(x1), p2 = __expf(x2), p3 = __expf(x3);
    float2 g0 = __half22float2(f0);
    float2 g1 = __half22float2(f1);
    float2 g2 = __half22float2(f2);
    float2 g3 = __half22float2(f3);
    ax = fmaf(p0, g0.x, ax); ay = fmaf(p0, g0.y, ay);
    ax = fmaf(p1, g1.x, ax); ay = fmaf(p1, g1.y, ay);
    ax = fmaf(p2, g2.x, ax); ay = fmaf(p2, g2.y, ay);
    ax = fmaf(p3, g3.x, ax); ay = fmaf(p3, g3.y, ay);
    s += (p0 + p1) + (p2 + p3);
  }
  for (; i < end; ++i) {
    int sr = srcs[i];
    float2 e = el2[sr];
    __half2 f = ft2[(size_t)sr * 64 + lane];
    float x = (h1 ? e.y : e.x) + erh;
    x = x > 0.f ? x : NEG_SLOPE * x;
    float p = __expf(x);
    float2 g = __half22float2(f);
    ax = fmaf(p, g.x, ax); ay = fmaf(p, g.y, ay);
    s += p;
  }
  float inv = 1.f / fmaxf(s, 1e-20f);
  out[(size_t)node * 64 + lane] = make_float2(ax * inv, ay * inv);
}

extern "C" void kernel_launch(void* const* d_in, const int* in_sizes, int n_in,
                              void* d_out, int out_size, void* d_ws, size_t ws_size,
                              hipStream_t stream) {
  const float* feat   = (const float*)d_in[0];
  const int*   src    = (const int*)d_in[1];
  const int*   dst    = (const int*)d_in[2];
  const float* W      = (const float*)d_in[3];
  const float* attn_l = (const float*)d_in[4];
  const float* attn_r = (const float*)d_in[5];
  float* out = (float*)d_out;

  char* base = (char*)d_ws;
  size_t off = 0;
  auto bump = [&](size_t bytes) -> void* {
    void* p = base + off;
    off = (off + bytes + 255) & ~(size_t)255;
    return p;
  };
  __half* ft16   = (__half*)bump(sizeof(__half) * N_NODES * 128);  // 12.8 MB
  float*  el     = (float*)bump(sizeof(float) * N_NODES * 2);
  float*  er     = (float*)bump(sizeof(float) * N_NODES * 2);
  int*    deg    = (int*)bump(sizeof(int) * N_NODES);
  int*    csum   = (int*)bump(sizeof(int) * NCH);
  int*    coff   = (int*)bump(sizeof(int) * NCH);
  int*    rowptr = (int*)bump(sizeof(int) * (N_NODES + 1));
  ushort* rank   = (ushort*)bump(sizeof(ushort) * N_EDGES);        // 3.2 MB
  int*    srcs   = (int*)bump(sizeof(int) * N_EDGES);              // 6.4 MB
  (void)ws_size; (void)in_sizes; (void)n_in; (void)out_size;

  (void)hipMemsetAsync(deg, 0, sizeof(int) * N_NODES, stream);

  k_deg<<<(N_EDGES / 4 + 255) / 256, 256, 0, stream>>>(dst, deg, rank);
  k_gemm<<<(N_NODES + 63) / 64, 256, 0, stream>>>(feat, W, attn_l, attn_r, ft16, el, er);
  k_scanA<<<NCH, 256, 0, stream>>>(deg, csum);
  k_scanB<<<1, 64, 0, stream>>>(csum, coff, rowptr);
  k_scanC<<<NCH, 256, 0, stream>>>(deg, coff, rowptr);
  k_sort<<<(N_EDGES / 4 + 255) / 256, 256, 0, stream>>>(src, dst, rank, rowptr, srcs);
  k_agg<<<(N_NODES * 64 + 255) / 256, 256, 0, stream>>>(srcs, rowptr,
      (const __half2*)ft16, (const float2*)el, (const float2*)er, (float2*)out);
}

// Round 8
// 327.113 us; speedup vs baseline: 2.6792x; 1.0284x over previous
//
#include <hip/hip_runtime.h>
#include <hip/hip_fp16.h>

#define N_NODES 50000
#define N_EDGES 1600000
#define IN_F 256
#define NEG_SLOPE 0.2f
#define CHUNK 1024
#define NCH ((N_NODES + CHUNK - 1) / CHUNK)   // 49

// ---- K1: ft16 = half(feat @ W) + fused el/er --------------------------------
// 64x128 tile, 256 thr, 4 rows x 8 cols per thread. f32 accumulate, fp16 store.
__global__ __launch_bounds__(256) void k_gemm(const float* __restrict__ feat,
                                              const float* __restrict__ W,
                                              const float* __restrict__ attn_l,
                                              const float* __restrict__ attn_r,
                                              __half* __restrict__ ft16,
                                              float* __restrict__ el,
                                              float* __restrict__ er) {
  __shared__ __align__(16) float Wl[32 * 128];   // 16 KB
  __shared__ __align__(16) float Fl[64 * 33];    // 8.4 KB, bank = (r+k)%32
  const int tid = threadIdx.x;
  const int cg = tid & 15;          // col group: cols cg*8 .. cg*8+7
  const int rg = tid >> 4;          // row group: rows rg*4 .. rg*4+3
  const int col0 = cg * 8, rowt = rg * 4;
  const int row0 = blockIdx.x * 64;
  float acc[4][8];
#pragma unroll
  for (int i = 0; i < 4; ++i)
#pragma unroll
    for (int j = 0; j < 8; ++j) acc[i][j] = 0.f;

  for (int kt = 0; kt < IN_F; kt += 32) {
    __syncthreads();
#pragma unroll
    for (int j = 0; j < 4; ++j) {                 // W chunk: 32x128
      int idx = tid + j * 256;
      ((float4*)Wl)[idx] = ((const float4*)(W + kt * 128))[idx];
    }
#pragma unroll
    for (int j = 0; j < 2; ++j) {                 // feat chunk: 64x32
      int r = j * 32 + (tid >> 3);
      int kk = (tid & 7) * 4;
      int grow = row0 + r;
      if (grow >= N_NODES) grow = N_NODES - 1;    // clamp; stores guarded
      float4 v = *(const float4*)(feat + (size_t)grow * IN_F + kt + kk);
      float* fp = &Fl[r * 33 + kk];
      fp[0] = v.x; fp[1] = v.y; fp[2] = v.z; fp[3] = v.w;
    }
    __syncthreads();
#pragma unroll
    for (int k = 0; k < 32; ++k) {
      float4 w0 = *(const float4*)&Wl[k * 128 + col0];
      float4 w1 = *(const float4*)&Wl[k * 128 + col0 + 4];
#pragma unroll
      for (int i = 0; i < 4; ++i) {
        float f = Fl[(rowt + i) * 33 + k];
        acc[i][0] = fmaf(f, w0.x, acc[i][0]);
        acc[i][1] = fmaf(f, w0.y, acc[i][1]);
        acc[i][2] = fmaf(f, w0.z, acc[i][2]);
        acc[i][3] = fmaf(f, w0.w, acc[i][3]);
        acc[i][4] = fmaf(f, w1.x, acc[i][4]);
        acc[i][5] = fmaf(f, w1.y, acc[i][5]);
        acc[i][6] = fmaf(f, w1.z, acc[i][6]);
        acc[i][7] = fmaf(f, w1.w, acc[i][7]);
      }
    }
  }
  // epilogue: fp16 store + fused per-head el/er
  float al[8], ar[8];
#pragma unroll
  for (int j = 0; j < 8; ++j) { al[j] = attn_l[col0 + j]; ar[j] = attn_r[col0 + j]; }
#pragma unroll
  for (int i = 0; i < 4; ++i) {
    int row = row0 + rowt + i;
    float sl = 0.f, sr = 0.f;
#pragma unroll
    for (int j = 0; j < 8; ++j) { sl = fmaf(acc[i][j], al[j], sl); sr = fmaf(acc[i][j], ar[j], sr); }
#pragma unroll
    for (int m = 1; m < 8; m <<= 1) { sl += __shfl_xor(sl, m, 64); sr += __shfl_xor(sr, m, 64); }
    if (row < N_NODES) {
      __half2 h0 = __floats2half2_rn(acc[i][0], acc[i][1]);
      __half2 h1 = __floats2half2_rn(acc[i][2], acc[i][3]);
      __half2 h2 = __floats2half2_rn(acc[i][4], acc[i][5]);
      __half2 h3 = __floats2half2_rn(acc[i][6], acc[i][7]);
      uint4 pk = make_uint4(*(unsigned*)&h0, *(unsigned*)&h1,
                            *(unsigned*)&h2, *(unsigned*)&h3);
      *(uint4*)(ft16 + (size_t)row * 128 + col0) = pk;
      if ((cg & 7) == 0) {
        int h = cg >> 3;                       // cg==0 -> head0, cg==8 -> head1
        el[row * 2 + h] = sl;
        er[row * 2 + h] = sr;
      }
    }
  }
}

// ---- K2: degree histogram + within-segment rank (atomic return) -------------
__global__ __launch_bounds__(256) void k_deg(const int* __restrict__ dst,
                                             int* __restrict__ deg,
                                             ushort* __restrict__ rank) {
  int t = blockIdx.x * 256 + threadIdx.x;
  if (t >= N_EDGES / 4) return;
  int4 d4 = ((const int4*)dst)[t];
  ushort4 r;
  r.x = (ushort)atomicAdd(&deg[d4.x], 1);
  r.y = (ushort)atomicAdd(&deg[d4.y], 1);
  r.z = (ushort)atomicAdd(&deg[d4.z], 1);
  r.w = (ushort)atomicAdd(&deg[d4.w], 1);
  ((ushort4*)rank)[t] = r;
}

// ---- K3a/b/c: chunked exclusive scan ----------------------------------------
__global__ __launch_bounds__(256) void k_scanA(const int* __restrict__ deg,
                                               int* __restrict__ csum) {
  __shared__ int ws[4];
  int b = blockIdx.x, tid = threadIdx.x, lane = tid & 63, w = tid >> 6;
  int i0 = b * CHUNK + tid * 4;
  int s = 0;
#pragma unroll
  for (int j = 0; j < 4; ++j) {
    int i = i0 + j;
    if (i < N_NODES) s += deg[i];
  }
#pragma unroll
  for (int m = 32; m > 0; m >>= 1) s += __shfl_xor(s, m, 64);
  if (lane == 0) ws[w] = s;
  __syncthreads();
  if (tid == 0) csum[b] = ws[0] + ws[1] + ws[2] + ws[3];
}

__global__ void k_scanB(const int* __restrict__ csum, int* __restrict__ coff,
                        int* __restrict__ rowptr) {
  int tid = threadIdx.x;                  // 64 threads
  int v = (tid < NCH) ? csum[tid] : 0;
  int x = v;
#pragma unroll
  for (int off = 1; off < 64; off <<= 1) {
    int y = __shfl_up(x, off, 64);
    if (tid >= off) x += y;
  }
  if (tid < NCH) coff[tid] = x - v;
  if (tid == NCH - 1) rowptr[N_NODES] = x;
}

__global__ __launch_bounds__(256) void k_scanC(const int* __restrict__ deg,
                                               const int* __restrict__ coff,
                                               int* __restrict__ rowptr) {
  __shared__ int wtot[4];
  int b = blockIdx.x, tid = threadIdx.x, lane = tid & 63, w = tid >> 6;
  int i0 = b * CHUNK + tid * 4;
  int d[4];
#pragma unroll
  for (int j = 0; j < 4; ++j) d[j] = (i0 + j < N_NODES) ? deg[i0 + j] : 0;
  int t1 = d[0] + d[1], t2 = t1 + d[2], t3 = t2 + d[3];
  int x = t3;
#pragma unroll
  for (int off = 1; off < 64; off <<= 1) {
    int y = __shfl_up(x, off, 64);
    if (lane >= off) x += y;
  }
  if (lane == 63) wtot[w] = x;
  __syncthreads();
  int woff = 0;
  for (int j = 0; j < w; ++j) woff += wtot[j];
  int excl = coff[b] + woff + (x - t3);
  int pre[4] = {0, d[0], t1, t2};
#pragma unroll
  for (int j = 0; j < 4; ++j) {
    int i = i0 + j;
    if (i < N_NODES) rowptr[i] = excl + pre[j];
  }
}

// ---- K4: counting-sort into 8B records {src, half2(p0,p1)} ------------------
// p computed ONCE per edge here (el/er are tiny L2-resident tables), so k_agg
// doesn't redo exp 32x per edge.
__device__ __forceinline__ void sort1(int s, int d, int rk,
                                      const int* __restrict__ rowptr,
                                      const float2* __restrict__ el2,
                                      const float2* __restrict__ er2,
                                      unsigned long long* __restrict__ rec) {
  float2 a = el2[s];
  float2 b = er2[d];
  float e0 = a.x + b.x, e1 = a.y + b.y;
  e0 = e0 > 0.f ? e0 : NEG_SLOPE * e0;
  e1 = e1 > 0.f ? e1 : NEG_SLOPE * e1;
  __half2 h = __floats2half2_rn(__expf(e0), __expf(e1));
  unsigned long long v =
      ((unsigned long long)(*(unsigned*)&h) << 32) | (unsigned)s;
  rec[rowptr[d] + rk] = v;
}

__global__ __launch_bounds__(256) void k_sortp(const int* __restrict__ src,
                                               const int* __restrict__ dst,
                                               const ushort* __restrict__ rank,
                                               const int* __restrict__ rowptr,
                                               const float2* __restrict__ el2,
                                               const float2* __restrict__ er2,
                                               unsigned long long* __restrict__ rec) {
  int t = blockIdx.x * 256 + threadIdx.x;
  if (t >= N_EDGES / 4) return;
  int4 s4 = ((const int4*)src)[t];
  int4 d4 = ((const int4*)dst)[t];
  ushort4 r4 = ((const ushort4*)rank)[t];
  sort1(s4.x, d4.x, r4.x, rowptr, el2, er2, rec);
  sort1(s4.y, d4.y, r4.y, rowptr, el2, er2, rec);
  sort1(s4.z, d4.z, r4.z, rowptr, el2, er2, rec);
  sort1(s4.w, d4.w, r4.w, rowptr, el2, er2, rec);
}

// ---- K5: aggregation, wave per node, unroll x8, fused softmax normalize -----
__global__ __launch_bounds__(256) void k_agg(const unsigned long long* __restrict__ rec,
                                             const int* __restrict__ rowptr,
                                             const __half2* __restrict__ ft2,
                                             float2* __restrict__ out) {
  int t = blockIdx.x * 256 + threadIdx.x;
  int node = t >> 6, lane = t & 63;
  if (node >= N_NODES) return;
  int beg = rowptr[node], end = rowptr[node + 1];
  bool h1 = lane >= 32;                 // lanes 0-31: head0 feats, 32-63: head1
  float ax = 0.f, ay = 0.f, s = 0.f;
  int i = beg;
  for (; i + 8 <= end; i += 8) {
    unsigned long long r[8];
#pragma unroll
    for (int j = 0; j < 8; ++j) r[j] = __builtin_nontemporal_load(&rec[i + j]);
    __half2 f[8];
#pragma unroll
    for (int j = 0; j < 8; ++j)
      f[j] = ft2[(size_t)(unsigned)(r[j] & 0xffffffffu) * 64 + lane];
#pragma unroll
    for (int j = 0; j < 8; ++j) {
      unsigned pw = (unsigned)(r[j] >> 32);
      float2 p = __half22float2(*(const __half2*)&pw);
      float a = h1 ? p.y : p.x;
      float2 g = __half22float2(f[j]);
      ax = fmaf(a, g.x, ax); ay = fmaf(a, g.y, ay);
      s += a;
    }
  }
  for (; i < end; ++i) {
    unsigned long long r = rec[i];
    unsigned pw = (unsigned)(r >> 32);
    float2 p = __half22float2(*(const __half2*)&pw);
    float a = h1 ? p.y : p.x;
    float2 g = __half22float2(ft2[(size_t)(unsigned)(r & 0xffffffffu) * 64 + lane]);
    ax = fmaf(a, g.x, ax); ay = fmaf(a, g.y, ay);
    s += a;
  }
  float inv = 1.f / fmaxf(s, 1e-20f);
  out[(size_t)node * 64 + lane] = make_float2(ax * inv, ay * inv);
}

extern "C" void kernel_launch(void* const* d_in, const int* in_sizes, int n_in,
                              void* d_out, int out_size, void* d_ws, size_t ws_size,
                              hipStream_t stream) {
  const float* feat   = (const float*)d_in[0];
  const int*   src    = (const int*)d_in[1];
  const int*   dst    = (const int*)d_in[2];
  const float* W      = (const float*)d_in[3];
  const float* attn_l = (const float*)d_in[4];
  const float* attn_r = (const float*)d_in[5];
  float* out = (float*)d_out;

  char* base = (char*)d_ws;
  size_t off = 0;
  auto bump = [&](size_t bytes) -> void* {
    void* p = base + off;
    off = (off + bytes + 255) & ~(size_t)255;
    return p;
  };
  __half* ft16   = (__half*)bump(sizeof(__half) * N_NODES * 128);  // 12.8 MB
  float*  el     = (float*)bump(sizeof(float) * N_NODES * 2);
  float*  er     = (float*)bump(sizeof(float) * N_NODES * 2);
  int*    deg    = (int*)bump(sizeof(int) * N_NODES);
  int*    csum   = (int*)bump(sizeof(int) * NCH);
  int*    coff   = (int*)bump(sizeof(int) * NCH);
  int*    rowptr = (int*)bump(sizeof(int) * (N_NODES + 1));
  ushort* rank   = (ushort*)bump(sizeof(ushort) * N_EDGES);        // 3.2 MB
  unsigned long long* rec =
      (unsigned long long*)bump(sizeof(unsigned long long) * N_EDGES); // 12.8 MB
  (void)ws_size; (void)in_sizes; (void)n_in; (void)out_size;

  (void)hipMemsetAsync(deg, 0, sizeof(int) * N_NODES, stream);

  k_deg<<<(N_EDGES / 4 + 255) / 256, 256, 0, stream>>>(dst, deg, rank);
  k_gemm<<<(N_NODES + 63) / 64, 256, 0, stream>>>(feat, W, attn_l, attn_r, ft16, el, er);
  k_scanA<<<NCH, 256, 0, stream>>>(deg, csum);
  k_scanB<<<1, 64, 0, stream>>>(csum, coff, rowptr);
  k_scanC<<<NCH, 256, 0, stream>>>(deg, coff, rowptr);
  k_sortp<<<(N_EDGES / 4 + 255) / 256, 256, 0, stream>>>(src, dst, rank, rowptr,
      (const float2*)el, (const float2*)er, rec);
  k_agg<<<(N_NODES * 64 + 255) / 256, 256, 0, stream>>>(rec, rowptr,
      (const __half2*)ft16, (float2*)out);
}

// Round 9
// 301.798 us; speedup vs baseline: 2.9039x; 1.0839x over previous
//
#include <hip/hip_runtime.h>
#include <hip/hip_fp16.h>

#define N_NODES 50000
#define N_EDGES 1600000
#define IN_F 256
#define NEG_SLOPE 0.2f
#define CHUNK 1024
#define NCH ((N_NODES + CHUNK - 1) / CHUNK)   // 49
#define NPAD 50048                             // padded node stride for deg8/off8
#define NCOPY 8

typedef _Float16 f16x8 __attribute__((ext_vector_type(8)));
typedef float f32x4 __attribute__((ext_vector_type(4)));

// ---- K1: ft16 = half(feat @ W) via MFMA f16 + fused el/er -------------------
// Block: 64 rows x 128 cols, 4 waves (wave w = rows w*16..+15, all 128 cols).
// Per k-step(32): stage feat[64][32]->Fl f16 [64][40] (pad), W[32][128]->Wt
// f16 [4][128][8] (g=k/8 subtile, 8 k innermost => b128 frag reads, 2-way free).
__global__ __launch_bounds__(256) void k_gemm(const float* __restrict__ feat,
                                              const float* __restrict__ W,
                                              const float* __restrict__ attn_l,
                                              const float* __restrict__ attn_r,
                                              __half* __restrict__ ft16,
                                              float* __restrict__ el,
                                              float* __restrict__ er) {
  __shared__ __align__(16) _Float16 Wt[4 * 128 * 8];   // 8 KB
  __shared__ __align__(16) _Float16 Fl[64 * 40];       // 5 KB (pad 32->40)
  const int tid = threadIdx.x;
  const int lane = tid & 63;
  const int w = tid >> 6;          // wave 0..3
  const int c0 = lane & 15;        // col-in-tile
  const int g = lane >> 4;         // k-subgroup 0..3
  const int row0 = blockIdx.x * 64;

  f32x4 acc[8];
#pragma unroll
  for (int t = 0; t < 8; ++t) acc[t] = f32x4{0.f, 0.f, 0.f, 0.f};

  // staging thread mappings
  const int fr = tid >> 2;               // feat row 0..63
  const int fk = (tid & 3) * 8;          // feat k-slot
  const int wc = tid & 127;              // W col 0..127
  const int wgp = tid >> 7;              // W g-pair 0/1

  for (int kt = 0; kt < IN_F; kt += 32) {
    __syncthreads();
    // feat tile: row fr, k kt+fk..+7 -> Fl[fr][fk..fk+7]
    {
      int grow = row0 + fr;
      if (grow >= N_NODES) grow = N_NODES - 1;   // clamp; epilogue guarded
      const float* fp = feat + (size_t)grow * IN_F + kt + fk;
      float4 v0 = *(const float4*)fp;
      float4 v1 = *(const float4*)(fp + 4);
      f16x8 h;
      h[0] = (_Float16)v0.x; h[1] = (_Float16)v0.y;
      h[2] = (_Float16)v0.z; h[3] = (_Float16)v0.w;
      h[4] = (_Float16)v1.x; h[5] = (_Float16)v1.y;
      h[6] = (_Float16)v1.z; h[7] = (_Float16)v1.w;
      *(f16x8*)&Fl[fr * 40 + fk] = h;
    }
    // W tile: col wc, g = wgp*2+gg, k = kt+g*8+j -> Wt[(g*128+wc)*8 + j]
#pragma unroll
    for (int gg = 0; gg < 2; ++gg) {
      int gw = wgp * 2 + gg;
      f16x8 h;
#pragma unroll
      for (int j = 0; j < 8; ++j)
        h[j] = (_Float16)W[(size_t)(kt + gw * 8 + j) * 128 + wc];
      *(f16x8*)&Wt[(gw * 128 + wc) * 8] = h;
    }
    __syncthreads();
    // compute: A-frag row = w*16 + c0, k-group g; B-frag col tile t
    f16x8 a = *(const f16x8*)&Fl[(w * 16 + c0) * 40 + g * 8];
#pragma unroll
    for (int t = 0; t < 8; ++t) {
      f16x8 b = *(const f16x8*)&Wt[(g * 128 + t * 16 + c0) * 8];
      acc[t] = __builtin_amdgcn_mfma_f32_16x16x32_f16(a, b, acc[t], 0, 0, 0);
    }
  }

  // epilogue: D[row=(g*4+r)][col=t*16+c0]; rows w*16+g*4+r
  float al8[8], ar8[8];
#pragma unroll
  for (int t = 0; t < 8; ++t) {
    al8[t] = attn_l[t * 16 + c0];
    ar8[t] = attn_r[t * 16 + c0];
  }
#pragma unroll
  for (int r = 0; r < 4; ++r) {
    int row = row0 + w * 16 + g * 4 + r;
    float sl0 = 0.f, sl1 = 0.f, sr0 = 0.f, sr1 = 0.f;
#pragma unroll
    for (int t = 0; t < 4; ++t) {
      sl0 = fmaf(acc[t][r], al8[t], sl0);
      sr0 = fmaf(acc[t][r], ar8[t], sr0);
    }
#pragma unroll
    for (int t = 4; t < 8; ++t) {
      sl1 = fmaf(acc[t][r], al8[t], sl1);
      sr1 = fmaf(acc[t][r], ar8[t], sr1);
    }
#pragma unroll
    for (int m = 1; m < 16; m <<= 1) {
      sl0 += __shfl_xor(sl0, m, 64);
      sl1 += __shfl_xor(sl1, m, 64);
      sr0 += __shfl_xor(sr0, m, 64);
      sr1 += __shfl_xor(sr1, m, 64);
    }
    if (row < N_NODES) {
#pragma unroll
      for (int t = 0; t < 8; ++t)
        ft16[(size_t)row * 128 + t * 16 + c0] = __float2half(acc[t][r]);
      if (c0 == 0) {
        el[row * 2 + 0] = sl0; el[row * 2 + 1] = sl1;
        er[row * 2 + 0] = sr0; er[row * 2 + 1] = sr1;
      }
    }
  }
}

// ---- K2: 8-way privatized degree histogram + within-copy rank ---------------
// copy = blockIdx&7 tracks XCD round-robin -> atomics stay XCD-local (perf
// heuristic only; correctness never depends on the mapping).
__global__ __launch_bounds__(256) void k_deg(const int* __restrict__ dst,
                                             int* __restrict__ deg8,
                                             ushort* __restrict__ rank) {
  int t = blockIdx.x * 256 + threadIdx.x;
  if (t >= N_EDGES / 4) return;
  int* mydeg = deg8 + (blockIdx.x & 7) * NPAD;
  int4 d4 = ((const int4*)dst)[t];
  ushort4 r;
  r.x = (ushort)atomicAdd(&mydeg[d4.x], 1);
  r.y = (ushort)atomicAdd(&mydeg[d4.y], 1);
  r.z = (ushort)atomicAdd(&mydeg[d4.z], 1);
  r.w = (ushort)atomicAdd(&mydeg[d4.w], 1);
  ((ushort4*)rank)[t] = r;
}

// ---- K3a/b/c: chunked exclusive scan over summed degrees --------------------
__global__ __launch_bounds__(256) void k_scanA(const int* __restrict__ deg8,
                                               int* __restrict__ csum) {
  __shared__ int ws[4];
  int b = blockIdx.x, tid = threadIdx.x, lane = tid & 63, w = tid >> 6;
  int i0 = b * CHUNK + tid * 4;
  int s = 0;
#pragma unroll
  for (int c = 0; c < NCOPY; ++c) {
    const int* dp = deg8 + c * NPAD;
#pragma unroll
    for (int j = 0; j < 4; ++j) {
      int i = i0 + j;
      if (i < N_NODES) s += dp[i];
    }
  }
#pragma unroll
  for (int m = 32; m > 0; m >>= 1) s += __shfl_xor(s, m, 64);
  if (lane == 0) ws[w] = s;
  __syncthreads();
  if (tid == 0) csum[b] = ws[0] + ws[1] + ws[2] + ws[3];
}

__global__ void k_scanB(const int* __restrict__ csum, int* __restrict__ coff,
                        int* __restrict__ rowptr) {
  int tid = threadIdx.x;                  // 64 threads
  int v = (tid < NCH) ? csum[tid] : 0;
  int x = v;
#pragma unroll
  for (int off = 1; off < 64; off <<= 1) {
    int y = __shfl_up(x, off, 64);
    if (tid >= off) x += y;
  }
  if (tid < NCH) coff[tid] = x - v;
  if (tid == NCH - 1) rowptr[N_NODES] = x;
}

__global__ __launch_bounds__(256) void k_scanC(const int* __restrict__ deg8,
                                               const int* __restrict__ coff,
                                               int* __restrict__ rowptr) {
  __shared__ int wtot[4];
  int b = blockIdx.x, tid = threadIdx.x, lane = tid & 63, w = tid >> 6;
  int i0 = b * CHUNK + tid * 4;
  int d[4] = {0, 0, 0, 0};
#pragma unroll
  for (int c = 0; c < NCOPY; ++c) {
    const int* dp = deg8 + c * NPAD;
#pragma unroll
    for (int j = 0; j < 4; ++j)
      if (i0 + j < N_NODES) d[j] += dp[i0 + j];
  }
  int t1 = d[0] + d[1], t2 = t1 + d[2], t3 = t2 + d[3];
  int x = t3;
#pragma unroll
  for (int off = 1; off < 64; off <<= 1) {
    int y = __shfl_up(x, off, 64);
    if (lane >= off) x += y;
  }
  if (lane == 63) wtot[w] = x;
  __syncthreads();
  int woff = 0;
  for (int j = 0; j < w; ++j) woff += wtot[j];
  int excl = coff[b] + woff + (x - t3);
  int pre[4] = {0, d[0], t1, t2};
#pragma unroll
  for (int j = 0; j < 4; ++j) {
    int i = i0 + j;
    if (i < N_NODES) rowptr[i] = excl + pre[j];
  }
}

// ---- K3d: per-node prefix over the 8 copies -> off8 -------------------------
__global__ __launch_bounds__(256) void k_off8(const int* __restrict__ deg8,
                                              const int* __restrict__ rowptr,
                                              int* __restrict__ off8) {
  int d = blockIdx.x * 256 + threadIdx.x;
  if (d >= N_NODES) return;
  int run = rowptr[d];
#pragma unroll
  for (int c = 0; c < NCOPY; ++c) {
    off8[c * NPAD + d] = run;
    run += deg8[c * NPAD + d];
  }
}

// ---- K4: counting-sort into 8B records {src, half2(p0,p1)} ------------------
__device__ __forceinline__ void sort1(int s, int d, int rk,
                                      const int* __restrict__ myoff,
                                      const float2* __restrict__ el2,
                                      const float2* __restrict__ er2,
                                      unsigned long long* __restrict__ rec) {
  float2 a = el2[s];
  float2 b = er2[d];
  float e0 = a.x + b.x, e1 = a.y + b.y;
  e0 = e0 > 0.f ? e0 : NEG_SLOPE * e0;
  e1 = e1 > 0.f ? e1 : NEG_SLOPE * e1;
  __half2 h = __floats2half2_rn(__expf(e0), __expf(e1));
  unsigned long long v =
      ((unsigned long long)(*(unsigned*)&h) << 32) | (unsigned)s;
  rec[myoff[d] + rk] = v;
}

__global__ __launch_bounds__(256) void k_sortp(const int* __restrict__ src,
                                               const int* __restrict__ dst,
                                               const ushort* __restrict__ rank,
                                               const int* __restrict__ off8,
                                               const float2* __restrict__ el2,
                                               const float2* __restrict__ er2,
                                               unsigned long long* __restrict__ rec) {
  int t = blockIdx.x * 256 + threadIdx.x;
  if (t >= N_EDGES / 4) return;
  const int* myoff = off8 + (blockIdx.x & 7) * NPAD;   // same mapping as k_deg
  int4 s4 = ((const int4*)src)[t];
  int4 d4 = ((const int4*)dst)[t];
  ushort4 r4 = ((const ushort4*)rank)[t];
  sort1(s4.x, d4.x, r4.x, myoff, el2, er2, rec);
  sort1(s4.y, d4.y, r4.y, myoff, el2, er2, rec);
  sort1(s4.z, d4.z, r4.z, myoff, el2, er2, rec);
  sort1(s4.w, d4.w, r4.w, myoff, el2, er2, rec);
}

// ---- K5: aggregation, wave per node, unroll x8, fused softmax normalize -----
__global__ __launch_bounds__(256) void k_agg(const unsigned long long* __restrict__ rec,
                                             const int* __restrict__ rowptr,
                                             const __half2* __restrict__ ft2,
                                             float2* __restrict__ out) {
  int t = blockIdx.x * 256 + threadIdx.x;
  int node = t >> 6, lane = t & 63;
  if (node >= N_NODES) return;
  int beg = rowptr[node], end = rowptr[node + 1];
  bool h1 = lane >= 32;                 // lanes 0-31: head0 feats, 32-63: head1
  float ax = 0.f, ay = 0.f, s = 0.f;
  int i = beg;
  for (; i + 8 <= end; i += 8) {
    unsigned long long r[8];
#pragma unroll
    for (int j = 0; j < 8; ++j) r[j] = __builtin_nontemporal_load(&rec[i + j]);
    __half2 f[8];
#pragma unroll
    for (int j = 0; j < 8; ++j)
      f[j] = ft2[(size_t)(unsigned)(r[j] & 0xffffffffu) * 64 + lane];
#pragma unroll
    for (int j = 0; j < 8; ++j) {
      unsigned pw = (unsigned)(r[j] >> 32);
      float2 p = __half22float2(*(const __half2*)&pw);
      float a = h1 ? p.y : p.x;
      float2 g = __half22float2(f[j]);
      ax = fmaf(a, g.x, ax); ay = fmaf(a, g.y, ay);
      s += a;
    }
  }
  for (; i < end; ++i) {
    unsigned long long r = rec[i];
    unsigned pw = (unsigned)(r >> 32);
    float2 p = __half22float2(*(const __half2*)&pw);
    float a = h1 ? p.y : p.x;
    float2 g = __half22float2(ft2[(size_t)(unsigned)(r & 0xffffffffu) * 64 + lane]);
    ax = fmaf(a, g.x, ax); ay = fmaf(a, g.y, ay);
    s += a;
  }
  float inv = 1.f / fmaxf(s, 1e-20f);
  out[(size_t)node * 64 + lane] = make_float2(ax * inv, ay * inv);
}

extern "C" void kernel_launch(void* const* d_in, const int* in_sizes, int n_in,
                              void* d_out, int out_size, void* d_ws, size_t ws_size,
                              hipStream_t stream) {
  const float* feat   = (const float*)d_in[0];
  const int*   src    = (const int*)d_in[1];
  const int*   dst    = (const int*)d_in[2];
  const float* W      = (const float*)d_in[3];
  const float* attn_l = (const float*)d_in[4];
  const float* attn_r = (const float*)d_in[5];
  float* out = (float*)d_out;

  char* base = (char*)d_ws;
  size_t off = 0;
  auto bump = [&](size_t bytes) -> void* {
    void* p = base + off;
    off = (off + bytes + 255) & ~(size_t)255;
    return p;
  };
  __half* ft16   = (__half*)bump(sizeof(__half) * N_NODES * 128);  // 12.8 MB
  float*  el     = (float*)bump(sizeof(float) * N_NODES * 2);
  float*  er     = (float*)bump(sizeof(float) * N_NODES * 2);
  int*    deg8   = (int*)bump(sizeof(int) * NCOPY * NPAD);         // 1.6 MB
  int*    off8   = (int*)bump(sizeof(int) * NCOPY * NPAD);         // 1.6 MB
  int*    csum   = (int*)bump(sizeof(int) * NCH);
  int*    coff   = (int*)bump(sizeof(int) * NCH);
  int*    rowptr = (int*)bump(sizeof(int) * (N_NODES + 1));
  ushort* rank   = (ushort*)bump(sizeof(ushort) * N_EDGES);        // 3.2 MB
  unsigned long long* rec =
      (unsigned long long*)bump(sizeof(unsigned long long) * N_EDGES); // 12.8 MB
  (void)ws_size; (void)in_sizes; (void)n_in; (void)out_size;

  (void)hipMemsetAsync(deg8, 0, sizeof(int) * NCOPY * NPAD, stream);

  k_deg<<<(N_EDGES / 4 + 255) / 256, 256, 0, stream>>>(dst, deg8, rank);
  k_gemm<<<(N_NODES + 63) / 64, 256, 0, stream>>>(feat, W, attn_l, attn_r, ft16, el, er);
  k_scanA<<<NCH, 256, 0, stream>>>(deg8, csum);
  k_scanB<<<1, 64, 0, stream>>>(csum, coff, rowptr);
  k_scanC<<<NCH, 256, 0, stream>>>(deg8, coff, rowptr);
  k_off8<<<(N_NODES + 255) / 256, 256, 0, stream>>>(deg8, rowptr, off8);
  k_sortp<<<(N_EDGES / 4 + 255) / 256, 256, 0, stream>>>(src, dst, rank, off8,
      (const float2*)el, (const float2*)er, rec);
  k_agg<<<(N_NODES * 64 + 255) / 256, 256, 0, stream>>>(rec, rowptr,
      (const __half2*)ft16, (float2*)out);
}